// Round 2
// baseline (605.807 us; speedup 1.0000x reference)
//
#include <hip/hip_runtime.h>

#define LC 64
#define NC 32

typedef float f4v __attribute__((ext_vector_type(4)));
typedef short s8v __attribute__((ext_vector_type(8)));

__device__ inline unsigned short f2bf(float x){
  union { float f; unsigned u; } v; v.f = x;
  unsigned r = v.u + 0x7fffu + ((v.u >> 16) & 1u);
  return (unsigned short)(r >> 16);
}
__device__ inline float bf2f(unsigned short b){
  union { unsigned u; float f; } v; v.u = ((unsigned)b) << 16;
  return v.f;
}
__device__ inline unsigned addbf2(unsigned a, unsigned b){
  float lo = bf2f((unsigned short)(a & 0xffffu)) + bf2f((unsigned short)(b & 0xffffu));
  float hi = bf2f((unsigned short)(a >> 16))     + bf2f((unsigned short)(b >> 16));
  return (unsigned)f2bf(lo) | ((unsigned)f2bf(hi) << 16);
}

// ---------------------------------------------------------------------------
// prep: Mt = 0.1*A^T ; T0 = I + Mt/6 ; Bt_bf16[n][k] = B[k][n] ; Ct_bf16[j][n] = C[n][j]
// plus: gbuf[0:2048] = h0 (e-vector slot k=0 for the carry scan)
__global__ void k_prep(const float* __restrict__ A, const float* __restrict__ B,
                       const float* __restrict__ C, const float* __restrict__ h0,
                       float* __restrict__ Mt, float* __restrict__ T0,
                       unsigned short* __restrict__ Bt, unsigned short* __restrict__ Ct,
                       float* __restrict__ gbuf){
  int i = blockIdx.x * 256 + threadIdx.x;
  const int tot = 65536 + 262144 + 262144 + 2048;
  for (; i < tot; i += gridDim.x * 256) {
    if (i < 65536) {
      int r = i >> 8, c = i & 255;
      float m = 0.1f * A[c * 256 + r];
      Mt[i] = m;
      T0[i] = m * (1.0f / 6.0f) + (r == c ? 1.0f : 0.0f);
    } else if (i < 65536 + 262144) {
      int j = i - 65536;            // n*1024 + k
      int n = j >> 10, k = j & 1023;
      Bt[j] = f2bf(B[k * 256 + n]);
    } else if (i < 65536 + 262144 + 262144) {
      int j = i - 65536 - 262144;   // col*256 + n
      int col = j >> 8, n = j & 255;
      Ct[j] = f2bf(C[n * 1024 + col]);
    } else {
      int j = i - 65536 - 262144 - 262144;
      gbuf[j] = h0[j];
    }
  }
}

// ---------------------------------------------------------------------------
// 256x256x256 f32 GEMM via hi/lo bf16 split MFMA:  Cout = alpha*(A@B) + addI*I
__global__ __launch_bounds__(256) void k_gemm256_hl(const float* __restrict__ A,
                                                    const float* __restrict__ B,
                                                    float* __restrict__ Cout,
                                                    float alpha, int addI){
  __shared__ unsigned short Ah[64][40], Al[64][40], Bh[64][40], Bl[64][40];
  int tid = threadIdx.x;
  int m0 = blockIdx.x * 64, n0 = blockIdx.y * 64;
  int w = tid >> 6, lane = tid & 63;
  int wr = w >> 1, wc = w & 1;
  int l15 = lane & 15, quad = lane >> 4;
  int q8 = quad * 8;
  f4v acc[2][2] = {};
  for (int kt = 0; kt < 256; kt += 32) {
    __syncthreads();
    // stage A (f32 -> hi/lo bf16), 64x32
#pragma unroll
    for (int q = 0; q < 2; ++q) {
      int id = q * 256 + tid;        // 0..511
      int row = id >> 3, c4 = id & 7;
      float4 vv = *reinterpret_cast<const float4*>(&A[(m0 + row) * 256 + kt + c4 * 4]);
      float vs[4] = {vv.x, vv.y, vv.z, vv.w};
      ushort4 h4, l4;
      unsigned short* hp = &h4.x; unsigned short* lp = &l4.x;
#pragma unroll
      for (int j = 0; j < 4; ++j) {
        unsigned short hi = f2bf(vs[j]);
        hp[j] = hi;
        lp[j] = f2bf(vs[j] - bf2f(hi));
      }
      *reinterpret_cast<ushort4*>(&Ah[row][c4 * 4]) = h4;
      *reinterpret_cast<ushort4*>(&Al[row][c4 * 4]) = l4;
    }
    // stage B transposed: Btile[col][k], coalesced reads along n
    {
      int col = tid & 63, kk0 = (tid >> 6) * 8;
#pragma unroll
      for (int j = 0; j < 8; ++j) {
        float v = B[(kt + kk0 + j) * 256 + n0 + col];
        unsigned short hi = f2bf(v);
        Bh[col][kk0 + j] = hi;
        Bl[col][kk0 + j] = f2bf(v - bf2f(hi));
      }
    }
    __syncthreads();
#pragma unroll
    for (int aq = 0; aq < 2; ++aq) {
      s8v ah = *reinterpret_cast<const s8v*>(&Ah[wr * 32 + aq * 16 + l15][q8]);
      s8v al = *reinterpret_cast<const s8v*>(&Al[wr * 32 + aq * 16 + l15][q8]);
#pragma unroll
      for (int bq = 0; bq < 2; ++bq) {
        s8v bh = *reinterpret_cast<const s8v*>(&Bh[wc * 32 + bq * 16 + l15][q8]);
        s8v bl = *reinterpret_cast<const s8v*>(&Bl[wc * 32 + bq * 16 + l15][q8]);
        acc[aq][bq] = __builtin_amdgcn_mfma_f32_16x16x32_bf16(ah, bh, acc[aq][bq], 0, 0, 0);
        acc[aq][bq] = __builtin_amdgcn_mfma_f32_16x16x32_bf16(ah, bl, acc[aq][bq], 0, 0, 0);
        acc[aq][bq] = __builtin_amdgcn_mfma_f32_16x16x32_bf16(al, bh, acc[aq][bq], 0, 0, 0);
      }
    }
  }
#pragma unroll
  for (int aq = 0; aq < 2; ++aq)
#pragma unroll
    for (int bq = 0; bq < 2; ++bq)
#pragma unroll
      for (int r = 0; r < 4; ++r) {
        int gm = m0 + wr * 32 + aq * 16 + quad * 4 + r;
        int gn = n0 + wc * 32 + bq * 16 + l15;
        Cout[gm * 256 + gn] = alpha * acc[aq][bq][r] + ((addI && gm == gn) ? 1.0f : 0.0f);
      }
}

// ---------------------------------------------------------------------------
// Kogge-Stone carry-scan round: gOut[r] = gIn[r] + (r>=rs ? gIn[r-rs]:0) @ P
// P supplied TRANSPOSED: PT[n][k] f32 (so c' = c@P uses B[k][n] = PT[n][k]).
// M=N=K=256, grid(4,4), hi/lo split bf16 MFMA.
__global__ __launch_bounds__(256) void k_scan(const float* __restrict__ gIn,
                                              const float* __restrict__ PT,
                                              float* __restrict__ gOut, int rs){
  __shared__ unsigned short Ah[64][40], Al[64][40], Bh[64][40], Bl[64][40];
  int tid = threadIdx.x;
  int m0 = blockIdx.x * 64, n0 = blockIdx.y * 64;
  int w = tid >> 6, lane = tid & 63;
  int wr = w >> 1, wc = w & 1;
  int l15 = lane & 15, quad = lane >> 4;
  int q8 = quad * 8;
  f4v acc[2][2];
  // init accumulator with pass-through term gIn at output coords
#pragma unroll
  for (int aq = 0; aq < 2; ++aq)
#pragma unroll
    for (int bq = 0; bq < 2; ++bq)
#pragma unroll
      for (int r = 0; r < 4; ++r) {
        int gm = m0 + wr * 32 + aq * 16 + quad * 4 + r;
        int gn = n0 + wc * 32 + bq * 16 + l15;
        acc[aq][bq][r] = gIn[gm * 256 + gn];
      }
  for (int kt = 0; kt < 256; kt += 32) {
    __syncthreads();
    // stage A = gIn shifted down by rs rows (rows < rs -> 0)
#pragma unroll
    for (int q = 0; q < 2; ++q) {
      int id = q * 256 + tid;
      int row = id >> 3, c4 = id & 7;
      int gr = m0 + row - rs;
      float4 vv;
      if (gr >= 0) vv = *reinterpret_cast<const float4*>(&gIn[gr * 256 + kt + c4 * 4]);
      else { vv.x = vv.y = vv.z = vv.w = 0.0f; }
      float vs[4] = {vv.x, vv.y, vv.z, vv.w};
      ushort4 h4, l4;
      unsigned short* hp = &h4.x; unsigned short* lp = &l4.x;
#pragma unroll
      for (int j = 0; j < 4; ++j) {
        unsigned short hi = f2bf(vs[j]);
        hp[j] = hi;
        lp[j] = f2bf(vs[j] - bf2f(hi));
      }
      *reinterpret_cast<ushort4*>(&Ah[row][c4 * 4]) = h4;
      *reinterpret_cast<ushort4*>(&Al[row][c4 * 4]) = l4;
    }
    // stage B from PT[n][k]: contiguous along k
#pragma unroll
    for (int q = 0; q < 2; ++q) {
      int id = q * 256 + tid;
      int col = id >> 3, c4 = id & 7;
      float4 vv = *reinterpret_cast<const float4*>(&PT[(n0 + col) * 256 + kt + c4 * 4]);
      float vs[4] = {vv.x, vv.y, vv.z, vv.w};
      ushort4 h4, l4;
      unsigned short* hp = &h4.x; unsigned short* lp = &l4.x;
#pragma unroll
      for (int j = 0; j < 4; ++j) {
        unsigned short hi = f2bf(vs[j]);
        hp[j] = hi;
        lp[j] = f2bf(vs[j] - bf2f(hi));
      }
      *reinterpret_cast<ushort4*>(&Bh[col][c4 * 4]) = h4;
      *reinterpret_cast<ushort4*>(&Bl[col][c4 * 4]) = l4;
    }
    __syncthreads();
#pragma unroll
    for (int aq = 0; aq < 2; ++aq) {
      s8v ah = *reinterpret_cast<const s8v*>(&Ah[wr * 32 + aq * 16 + l15][q8]);
      s8v al = *reinterpret_cast<const s8v*>(&Al[wr * 32 + aq * 16 + l15][q8]);
#pragma unroll
      for (int bq = 0; bq < 2; ++bq) {
        s8v bh = *reinterpret_cast<const s8v*>(&Bh[wc * 32 + bq * 16 + l15][q8]);
        s8v bl = *reinterpret_cast<const s8v*>(&Bl[wc * 32 + bq * 16 + l15][q8]);
        acc[aq][bq] = __builtin_amdgcn_mfma_f32_16x16x32_bf16(ah, bh, acc[aq][bq], 0, 0, 0);
        acc[aq][bq] = __builtin_amdgcn_mfma_f32_16x16x32_bf16(ah, bl, acc[aq][bq], 0, 0, 0);
        acc[aq][bq] = __builtin_amdgcn_mfma_f32_16x16x32_bf16(al, bh, acc[aq][bq], 0, 0, 0);
      }
    }
  }
#pragma unroll
  for (int aq = 0; aq < 2; ++aq)
#pragma unroll
    for (int bq = 0; bq < 2; ++bq)
#pragma unroll
      for (int r = 0; r < 4; ++r) {
        int gm = m0 + wr * 32 + aq * 16 + quad * 4 + r;
        int gn = n0 + wc * 32 + bq * 16 + l15;
        gOut[gm * 256 + gn] = acc[aq][bq][r];
      }
}

// ---------------------------------------------------------------------------
// Et_bf16[m][n] = AdT[m][n] - I
__global__ void k_convert(const float* __restrict__ AdT,
                          unsigned short* __restrict__ Et){
  int i = blockIdx.x * 256 + threadIdx.x;
  for (; i < 65536; i += gridDim.x * 256) {
    int m = i >> 8, n = i & 255;
    Et[i] = f2bf(AdT[i] - (m == n ? 1.0f : 0.0f));
  }
}

// ---------------------------------------------------------------------------
// u_bf16 = bf16(x @ B) : M=16384, K=1024, N=256. grid(128,2)
__global__ __launch_bounds__(256) void k_gemm_u(const float* __restrict__ x,
                                                const unsigned short* __restrict__ Bt,
                                                unsigned short* __restrict__ u){
  __shared__ unsigned short Atile[128][40];
  __shared__ unsigned short Btile[128][40];
  int tid = threadIdx.x;
  int m0 = blockIdx.x * 128, n0 = blockIdx.y * 128;
  int w = tid >> 6, lane = tid & 63;
  int wr = w >> 1, wc = w & 1;
  int l15 = lane & 15, quad = lane >> 4;
  int q8 = quad * 8;
  f4v acc[4][4] = {};
  for (int kt = 0; kt < 1024; kt += 32) {
    __syncthreads();
#pragma unroll
    for (int q = 0; q < 4; ++q) {
      int id = q * 256 + tid;        // 1024 float4 total
      int row = id >> 3, c4 = id & 7;
      float4 vv = *reinterpret_cast<const float4*>(&x[(m0 + row) * 1024 + kt + c4 * 4]);
      ushort4 hv;
      hv.x = f2bf(vv.x); hv.y = f2bf(vv.y); hv.z = f2bf(vv.z); hv.w = f2bf(vv.w);
      *reinterpret_cast<ushort4*>(&Atile[row][c4 * 4]) = hv;
    }
#pragma unroll
    for (int q = 0; q < 2; ++q) {
      int id = q * 256 + tid;        // 512 uint4 total
      int row = id >> 2, c8 = id & 3;
      uint4 vv = *reinterpret_cast<const uint4*>(&Bt[(n0 + row) * 1024 + kt + c8 * 8]);
      *reinterpret_cast<uint4*>(&Btile[row][c8 * 8]) = vv;
    }
    __syncthreads();
    s8v af[4], bf[4];
#pragma unroll
    for (int aq = 0; aq < 4; ++aq)
      af[aq] = *reinterpret_cast<const s8v*>(&Atile[wr * 64 + aq * 16 + l15][q8]);
#pragma unroll
    for (int bq = 0; bq < 4; ++bq)
      bf[bq] = *reinterpret_cast<const s8v*>(&Btile[wc * 64 + bq * 16 + l15][q8]);
#pragma unroll
    for (int aq = 0; aq < 4; ++aq)
#pragma unroll
      for (int bq = 0; bq < 4; ++bq)
        acc[aq][bq] = __builtin_amdgcn_mfma_f32_16x16x32_bf16(af[aq], bf[bq], acc[aq][bq], 0, 0, 0);
  }
#pragma unroll
  for (int aq = 0; aq < 4; ++aq)
#pragma unroll
    for (int bq = 0; bq < 4; ++bq)
#pragma unroll
      for (int r = 0; r < 4; ++r) {
        int gm = m0 + wr * 64 + aq * 16 + quad * 4 + r;
        int gn = n0 + wc * 64 + bq * 16 + l15;
        u[gm * 256 + gn] = f2bf(acc[aq][bq][r]);
      }
}

// ---------------------------------------------------------------------------
// phase 1: per-(b,chunk) local scan h_t = h_{t-1} + h_{t-1}@E + u_t, zero init.
// 16 blocks x 16 units; writes hs (bf16 local states) and ff (f32 chunk finals).
__global__ __launch_bounds__(256, 1) void k_phase1(const unsigned short* __restrict__ u,
                                                   const unsigned short* __restrict__ Et,
                                                   unsigned short* __restrict__ hs,
                                                   float* __restrict__ ff){
  __shared__ unsigned short hbuf[2][16][264];
  int tid = threadIdx.x, w = tid >> 6, lane = tid & 63;
  int l15 = lane & 15, quad = lane >> 4;
  int U0 = blockIdx.x * 16;
  s8v e[4][8];
#pragma unroll
  for (int ct = 0; ct < 4; ++ct) {
    int col = w * 64 + ct * 16 + l15;
#pragma unroll
    for (int kt = 0; kt < 8; ++kt)
      e[ct][kt] = *reinterpret_cast<const s8v*>(&Et[col * 256 + kt * 32 + quad * 8]);
  }
  int rowbase[4];
#pragma unroll
  for (int r = 0; r < 4; ++r) {
    int g = U0 + quad * 4 + r;
    rowbase[r] = ((g >> 5) * 2048 + (g & 31) * 64) * 256;
  }
  for (int i = tid; i < 16 * 264; i += 256) hbuf[0][0][i] = 0;
  f4v acc[4] = {};
  __syncthreads();
  int cur = 0;
  for (int t = 0; t < LC; ++t) {
    s8v af[8];
#pragma unroll
    for (int kt = 0; kt < 8; ++kt)
      af[kt] = *reinterpret_cast<const s8v*>(&hbuf[cur][l15][kt * 32 + quad * 8]);
    float uv[4][4];
#pragma unroll
    for (int r = 0; r < 4; ++r)
#pragma unroll
      for (int ct = 0; ct < 4; ++ct)
        uv[r][ct] = bf2f(u[rowbase[r] + t * 256 + w * 64 + ct * 16 + l15]);
#pragma unroll
    for (int kt = 0; kt < 8; ++kt)
#pragma unroll
      for (int ct = 0; ct < 4; ++ct)
        acc[ct] = __builtin_amdgcn_mfma_f32_16x16x32_bf16(af[kt], e[ct][kt], acc[ct], 0, 0, 0);
    int nxt = cur ^ 1;
#pragma unroll
    for (int ct = 0; ct < 4; ++ct)
#pragma unroll
      for (int r = 0; r < 4; ++r) {
        acc[ct][r] += uv[r][ct];
        hbuf[nxt][quad * 4 + r][w * 64 + ct * 16 + l15] = f2bf(acc[ct][r]);
      }
    __syncthreads();
    int ul = w * 4 + quad, seg = l15;
    uint4 d0 = *reinterpret_cast<const uint4*>(&hbuf[nxt][ul][seg * 16]);
    uint4 d1 = *reinterpret_cast<const uint4*>(&hbuf[nxt][ul][seg * 16 + 8]);
    int g = U0 + ul;
    int hrow = ((g >> 5) * 2048 + (g & 31) * 64 + t) * 256;
    *reinterpret_cast<uint4*>(&hs[hrow + seg * 16]) = d0;
    *reinterpret_cast<uint4*>(&hs[hrow + seg * 16 + 8]) = d1;
    cur = nxt;
  }
#pragma unroll
  for (int ct = 0; ct < 4; ++ct)
#pragma unroll
    for (int r = 0; r < 4; ++r) {
      int g = U0 + quad * 4 + r;
      ff[(((g & 31) << 3) + (g >> 5)) * 256 + w * 64 + ct * 16 + l15] = acc[ct][r];
    }
}

// ---------------------------------------------------------------------------
// phase 3: carry expansion scan: acc_t = acc_{t-1} + acc_{t-1}@E (acc_0=carry),
// RMW hs[t] += acc_t.  Same structure as phase 1.
__global__ __launch_bounds__(256, 1) void k_phase3(const float* __restrict__ carry,
                                                   const unsigned short* __restrict__ Et,
                                                   unsigned short* __restrict__ hs){
  __shared__ unsigned short hbuf[2][16][264];
  int tid = threadIdx.x, w = tid >> 6, lane = tid & 63;
  int l15 = lane & 15, quad = lane >> 4;
  int U0 = blockIdx.x * 16;
  s8v e[4][8];
#pragma unroll
  for (int ct = 0; ct < 4; ++ct) {
    int col = w * 64 + ct * 16 + l15;
#pragma unroll
    for (int kt = 0; kt < 8; ++kt)
      e[ct][kt] = *reinterpret_cast<const s8v*>(&Et[col * 256 + kt * 32 + quad * 8]);
  }
  f4v acc[4];
#pragma unroll
  for (int ct = 0; ct < 4; ++ct)
#pragma unroll
    for (int r = 0; r < 4; ++r) {
      int g = U0 + quad * 4 + r;
      acc[ct][r] = carry[(((g & 31) << 3) + (g >> 5)) * 256 + w * 64 + ct * 16 + l15];
      hbuf[0][quad * 4 + r][w * 64 + ct * 16 + l15] = f2bf(acc[ct][r]);
    }
  __syncthreads();
  int cur = 0;
  for (int t = 0; t < LC; ++t) {
    s8v af[8];
#pragma unroll
    for (int kt = 0; kt < 8; ++kt)
      af[kt] = *reinterpret_cast<const s8v*>(&hbuf[cur][l15][kt * 32 + quad * 8]);
#pragma unroll
    for (int kt = 0; kt < 8; ++kt)
#pragma unroll
      for (int ct = 0; ct < 4; ++ct)
        acc[ct] = __builtin_amdgcn_mfma_f32_16x16x32_bf16(af[kt], e[ct][kt], acc[ct], 0, 0, 0);
    int nxt = cur ^ 1;
#pragma unroll
    for (int ct = 0; ct < 4; ++ct)
#pragma unroll
      for (int r = 0; r < 4; ++r)
        hbuf[nxt][quad * 4 + r][w * 64 + ct * 16 + l15] = f2bf(acc[ct][r]);
    __syncthreads();
    int ul = w * 4 + quad, seg = l15;
    uint4 d0 = *reinterpret_cast<const uint4*>(&hbuf[nxt][ul][seg * 16]);
    uint4 d1 = *reinterpret_cast<const uint4*>(&hbuf[nxt][ul][seg * 16 + 8]);
    int g = U0 + ul;
    int hrow = ((g >> 5) * 2048 + (g & 31) * 64 + t) * 256;
    uint4 o0 = *reinterpret_cast<const uint4*>(&hs[hrow + seg * 16]);
    uint4 o1 = *reinterpret_cast<const uint4*>(&hs[hrow + seg * 16 + 8]);
    uint4 s0, s1;
    s0.x = addbf2(d0.x, o0.x); s0.y = addbf2(d0.y, o0.y);
    s0.z = addbf2(d0.z, o0.z); s0.w = addbf2(d0.w, o0.w);
    s1.x = addbf2(d1.x, o1.x); s1.y = addbf2(d1.y, o1.y);
    s1.z = addbf2(d1.z, o1.z); s1.w = addbf2(d1.w, o1.w);
    *reinterpret_cast<uint4*>(&hs[hrow + seg * 16]) = s0;
    *reinterpret_cast<uint4*>(&hs[hrow + seg * 16 + 8]) = s1;
    cur = nxt;
  }
}

// ---------------------------------------------------------------------------
// y = hs @ C + x*D : M=16384, K=256, N=1024. grid(128,8)
__global__ __launch_bounds__(256) void k_gemm_y(const unsigned short* __restrict__ hs,
                                                const unsigned short* __restrict__ Ct,
                                                const float* __restrict__ x,
                                                const float* __restrict__ D,
                                                float* __restrict__ y){
  __shared__ unsigned short Atile[128][40];
  __shared__ unsigned short Btile[128][40];
  int tid = threadIdx.x;
  int m0 = blockIdx.x * 128, n0 = blockIdx.y * 128;
  int w = tid >> 6, lane = tid & 63;
  int wr = w >> 1, wc = w & 1;
  int l15 = lane & 15, quad = lane >> 4;
  int q8 = quad * 8;
  f4v acc[4][4] = {};
  for (int kt = 0; kt < 256; kt += 32) {
    __syncthreads();
#pragma unroll
    for (int q = 0; q < 2; ++q) {
      int id = q * 256 + tid;
      int row = id >> 2, c8 = id & 3;
      uint4 av = *reinterpret_cast<const uint4*>(&hs[(m0 + row) * 256 + kt + c8 * 8]);
      *reinterpret_cast<uint4*>(&Atile[row][c8 * 8]) = av;
      uint4 bv = *reinterpret_cast<const uint4*>(&Ct[(n0 + row) * 256 + kt + c8 * 8]);
      *reinterpret_cast<uint4*>(&Btile[row][c8 * 8]) = bv;
    }
    __syncthreads();
    s8v af[4], bf[4];
#pragma unroll
    for (int aq = 0; aq < 4; ++aq)
      af[aq] = *reinterpret_cast<const s8v*>(&Atile[wr * 64 + aq * 16 + l15][q8]);
#pragma unroll
    for (int bq = 0; bq < 4; ++bq)
      bf[bq] = *reinterpret_cast<const s8v*>(&Btile[wc * 64 + bq * 16 + l15][q8]);
#pragma unroll
    for (int aq = 0; aq < 4; ++aq)
#pragma unroll
      for (int bq = 0; bq < 4; ++bq)
        acc[aq][bq] = __builtin_amdgcn_mfma_f32_16x16x32_bf16(af[aq], bf[bq], acc[aq][bq], 0, 0, 0);
  }
#pragma unroll
  for (int bq = 0; bq < 4; ++bq) {
    int gn = n0 + wc * 64 + bq * 16 + l15;
    float dv = D[gn];
#pragma unroll
    for (int aq = 0; aq < 4; ++aq)
#pragma unroll
      for (int r = 0; r < 4; ++r) {
        int gm = m0 + wr * 64 + aq * 16 + quad * 4 + r;
        y[gm * 1024 + gn] = acc[aq][bq][r] + x[gm * 1024 + gn] * dv;
      }
  }
}

// ---------------------------------------------------------------------------
extern "C" void kernel_launch(void* const* d_in, const int* in_sizes, int n_in,
                              void* d_out, int out_size, void* d_ws, size_t ws_size,
                              hipStream_t stream) {
  (void)in_sizes; (void)n_in; (void)out_size; (void)ws_size;
  const float* x  = (const float*)d_in[0];
  const float* A  = (const float*)d_in[1];
  const float* B  = (const float*)d_in[2];
  const float* C  = (const float*)d_in[3];
  const float* D  = (const float*)d_in[4];
  const float* h0 = (const float*)d_in[5];
  float* y = (float*)d_out;

  char* ws = (char*)d_ws;
  size_t off = 0;
  auto alloc = [&](size_t bytes) { void* p = ws + off; off += (bytes + 255) & ~(size_t)255; return p; };
  float* Ttmp0 = (float*)alloc(262144);
  float* Ttmp1 = (float*)alloc(262144);
  float* Mt    = (float*)alloc(262144);
  float* AdT   = (float*)alloc(262144);
  float* A64T  = (float*)alloc(262144);   // P1^T
  float* P2T   = (float*)alloc(262144);
  float* P4T   = (float*)alloc(262144);
  float* P8T   = (float*)alloc(262144);
  float* P16T  = (float*)alloc(262144);
  unsigned short* Et = (unsigned short*)alloc(131072);
  float* gbuf  = (float*)alloc(33 * 2048 * 4);   // e-vector: [h0 | ff(32 chunks)]
  float* S1    = (float*)alloc(262144);
  float* S2    = (float*)alloc(262144);
  unsigned short* Bt = (unsigned short*)alloc(524288);
  unsigned short* Ct = (unsigned short*)alloc(524288);
  unsigned short* u  = (unsigned short*)alloc(8388608);
  unsigned short* hs = (unsigned short*)alloc(8388608);
  float* ff = gbuf + 2048;   // chunk finals land at e-slots 1..32

  k_prep<<<2304, 256, 0, stream>>>(A, B, C, h0, Mt, Ttmp0, Bt, Ct, gbuf);

  dim3 g44(4, 4);
  // Taylor (Horner, 6 terms): T0 already = I + Mt/6
  k_gemm256_hl<<<g44, 256, 0, stream>>>(Mt, Ttmp0, Ttmp1, 1.0f / 5.0f, 1);
  k_gemm256_hl<<<g44, 256, 0, stream>>>(Mt, Ttmp1, Ttmp0, 1.0f / 4.0f, 1);
  k_gemm256_hl<<<g44, 256, 0, stream>>>(Mt, Ttmp0, Ttmp1, 1.0f / 3.0f, 1);
  k_gemm256_hl<<<g44, 256, 0, stream>>>(Mt, Ttmp1, Ttmp0, 1.0f / 2.0f, 1);
  k_gemm256_hl<<<g44, 256, 0, stream>>>(Mt, Ttmp0, AdT, 1.0f, 1);
  // squarings: AdT -> A64T  (A_d^T squared 6 times)
  k_gemm256_hl<<<g44, 256, 0, stream>>>(AdT, AdT, Ttmp0, 1.0f, 0);
  k_gemm256_hl<<<g44, 256, 0, stream>>>(Ttmp0, Ttmp0, Ttmp1, 1.0f, 0);
  k_gemm256_hl<<<g44, 256, 0, stream>>>(Ttmp1, Ttmp1, Ttmp0, 1.0f, 0);
  k_gemm256_hl<<<g44, 256, 0, stream>>>(Ttmp0, Ttmp0, Ttmp1, 1.0f, 0);
  k_gemm256_hl<<<g44, 256, 0, stream>>>(Ttmp1, Ttmp1, Ttmp0, 1.0f, 0);
  k_gemm256_hl<<<g44, 256, 0, stream>>>(Ttmp0, Ttmp0, A64T, 1.0f, 0);
  // chunk-stride powers (transposed space): P_{2k}^T = (P_k^T)^2
  k_gemm256_hl<<<g44, 256, 0, stream>>>(A64T, A64T, P2T, 1.0f, 0);
  k_gemm256_hl<<<g44, 256, 0, stream>>>(P2T, P2T, P4T, 1.0f, 0);
  k_gemm256_hl<<<g44, 256, 0, stream>>>(P4T, P4T, P8T, 1.0f, 0);
  k_gemm256_hl<<<g44, 256, 0, stream>>>(P8T, P8T, P16T, 1.0f, 0);

  k_convert<<<256, 256, 0, stream>>>(AdT, Et);

  k_gemm_u<<<dim3(128, 2), 256, 0, stream>>>(x, Bt, u);
  k_phase1<<<16, 256, 0, stream>>>(u, Et, hs, ff);
  // Kogge-Stone carry scan over 32 chunks (rows = chunk*8 + batch)
  k_scan<<<g44, 256, 0, stream>>>(gbuf, A64T, S1, 8);
  k_scan<<<g44, 256, 0, stream>>>(S1, P2T, S2, 16);
  k_scan<<<g44, 256, 0, stream>>>(S2, P4T, S1, 32);
  k_scan<<<g44, 256, 0, stream>>>(S1, P8T, S2, 64);
  k_scan<<<g44, 256, 0, stream>>>(S2, P16T, S1, 128);
  k_phase3<<<16, 256, 0, stream>>>(S1, Et, hs);
  k_gemm_y<<<dim3(128, 8), 256, 0, stream>>>(hs, Ct, x, D, y);
}

// Round 3
// 550.329 us; speedup vs baseline: 1.1008x; 1.1008x over previous
//
#include <hip/hip_runtime.h>

typedef float f4v __attribute__((ext_vector_type(4)));
typedef short s8v __attribute__((ext_vector_type(8)));

__device__ __forceinline__ unsigned short f2bf(float x){
  union { float f; unsigned u; } v; v.f = x;
  unsigned r = v.u + 0x7fffu + ((v.u >> 16) & 1u);
  return (unsigned short)(r >> 16);
}
__device__ __forceinline__ float bf2f(unsigned short b){
  union { unsigned u; float f; } v; v.u = ((unsigned)b) << 16;
  return v.f;
}
// split 8 consecutive f32 into hi/lo bf16 fragments
__device__ __forceinline__ void split8(const float* __restrict__ p, s8v& h, s8v& l){
  float4 v0 = *reinterpret_cast<const float4*>(p);
  float4 v1 = *reinterpret_cast<const float4*>(p + 4);
  float a[8] = {v0.x, v0.y, v0.z, v0.w, v1.x, v1.y, v1.z, v1.w};
#pragma unroll
  for (int j = 0; j < 8; ++j) {
    unsigned short hi = f2bf(a[j]);
    h[j] = (short)hi;
    l[j] = (short)f2bf(a[j] - bf2f(hi));
  }
}
__device__ __forceinline__ void zero8(s8v& v){
#pragma unroll
  for (int j = 0; j < 8; ++j) v[j] = 0;
}

// grid barrier: co-resident grid only. One dedicated counter per barrier site.
__device__ __forceinline__ void gbar(unsigned* ctr, unsigned nb){
  __syncthreads();                     // drains each wave's vmcnt -> stores in L2
  if (threadIdx.x == 0) {
    __threadfence();                   // cross-XCD writeback
    __hip_atomic_fetch_add(ctr, 1u, __ATOMIC_ACQ_REL, __HIP_MEMORY_SCOPE_AGENT);
    while (__hip_atomic_load(ctr, __ATOMIC_ACQUIRE, __HIP_MEMORY_SCOPE_AGENT) < nb)
      __builtin_amdgcn_s_sleep(1);
    __threadfence();                   // invalidate caches before consuming
  }
  __syncthreads();
}

// ---------------------------------------------------------------------------
// prep: Mt = 0.1*A^T ; Tp0 = I + Mt/4 (Taylor-4 innermost) ;
//       Bt[n][k]=B[k][n] bf16 ; Ct[j][n]=C[n][j] bf16
__global__ void k_prep(const float* __restrict__ A, const float* __restrict__ B,
                       const float* __restrict__ C,
                       float* __restrict__ Mt, float* __restrict__ Tp0,
                       unsigned short* __restrict__ Bt, unsigned short* __restrict__ Ct){
  int i = blockIdx.x * 256 + threadIdx.x;
  const int tot = 65536 + 262144 + 262144;
  for (; i < tot; i += gridDim.x * 256) {
    if (i < 65536) {
      int r = i >> 8, c = i & 255;
      float m = 0.1f * A[c * 256 + r];
      Mt[i] = m;
      Tp0[i] = m * 0.25f + (r == c ? 1.0f : 0.0f);
    } else if (i < 65536 + 262144) {
      int j = i - 65536;            // n*1024 + k
      int n = j >> 10, k = j & 1023;
      Bt[j] = f2bf(B[k * 256 + n]);
    } else {
      int j = i - 65536 - 262144;   // col*256 + n
      int col = j >> 8, n = j & 255;
      Ct[j] = f2bf(C[n * 1024 + col]);
    }
  }
}

// ---------------------------------------------------------------------------
// chain mega-kernel (128 blocks): Taylor-4 expm (3 GEMM phases) then power
// stack QS[j] = (A_d^T)^(j+1), j=0..15, via log-doubling (4 phases).
// All matrices in transposed (Q) space. QS rows are k-contiguous -> direct
// MFMA fragment loads. Also writes Et = Q1 - I (bf16).
__global__ __launch_bounds__(256, 1) void k_chain(const float* __restrict__ Mt,
    float* __restrict__ Tp0, float* __restrict__ Tp1,
    unsigned short* __restrict__ QSh, unsigned short* __restrict__ QSl,
    unsigned short* __restrict__ Et, unsigned* __restrict__ ctrs){
  __shared__ unsigned short Bh[64][40], Bl[64][40];
  int tid = threadIdx.x, lane = tid & 63, w = tid >> 6;
  int wr = w >> 1, wc = w & 1, l15 = lane & 15, quad = lane >> 4, q8 = quad * 8;
  int bid = blockIdx.x;
  int bc = 0;
  // ---- Taylor phases: out = alpha*(Mt @ Bsrc) + I
  const float alphas[3] = {1.0f / 3.0f, 0.5f, 1.0f};
#pragma unroll 1
  for (int ph = 0; ph < 3; ++ph) {
    const float* Bsrc = (ph == 1) ? Tp1 : Tp0;
    float* Odst = (ph == 0) ? Tp1 : Tp0;
    if (bid < 16) {
      int m0 = (bid >> 2) * 64, n0 = (bid & 3) * 64;
      f4v acc[2][2] = {};
      for (int kt = 0; kt < 256; kt += 32) {
        __syncthreads();
        {
          int col = tid & 63, kk0 = (tid >> 6) * 8;
#pragma unroll
          for (int j = 0; j < 8; ++j) {
            float v = Bsrc[(kt + kk0 + j) * 256 + n0 + col];
            unsigned short hi = f2bf(v);
            Bh[col][kk0 + j] = hi;
            Bl[col][kk0 + j] = f2bf(v - bf2f(hi));
          }
        }
        __syncthreads();
#pragma unroll
        for (int aq = 0; aq < 2; ++aq) {
          s8v ah, al;
          split8(&Mt[(m0 + wr * 32 + aq * 16 + l15) * 256 + kt + q8], ah, al);
#pragma unroll
          for (int bq = 0; bq < 2; ++bq) {
            s8v bh = *reinterpret_cast<const s8v*>(&Bh[wc * 32 + bq * 16 + l15][q8]);
            s8v bl = *reinterpret_cast<const s8v*>(&Bl[wc * 32 + bq * 16 + l15][q8]);
            acc[aq][bq] = __builtin_amdgcn_mfma_f32_16x16x32_bf16(ah, bh, acc[aq][bq], 0, 0, 0);
            acc[aq][bq] = __builtin_amdgcn_mfma_f32_16x16x32_bf16(ah, bl, acc[aq][bq], 0, 0, 0);
            acc[aq][bq] = __builtin_amdgcn_mfma_f32_16x16x32_bf16(al, bh, acc[aq][bq], 0, 0, 0);
          }
        }
      }
#pragma unroll
      for (int aq = 0; aq < 2; ++aq)
#pragma unroll
        for (int bq = 0; bq < 2; ++bq)
#pragma unroll
          for (int r = 0; r < 4; ++r) {
            int gm = m0 + wr * 32 + aq * 16 + quad * 4 + r;
            int gn = n0 + wc * 32 + bq * 16 + l15;
            float raw = alphas[ph] * acc[aq][bq][r];
            float v = raw + (gm == gn ? 1.0f : 0.0f);
            if (ph < 2) {
              Odst[gm * 256 + gn] = v;
            } else {
              unsigned short hi = f2bf(v);
              QSh[gm * 256 + gn] = hi;
              QSl[gm * 256 + gn] = f2bf(v - bf2f(hi));
              Et[gm * 256 + gn] = f2bf(raw);   // Q1 - I
            }
          }
    }
    gbar(&ctrs[bc++], 128);
  }
  // ---- power stack: for d in {1,2,4,8}: QS[d+j] = QS[j] @ QS[d-1], j<d
#pragma unroll 1
  for (int d = 1; d <= 8; d <<= 1) {
    int ntiles = d * 16;
    if (bid < ntiles) {
      int mt = bid >> 2, nt = bid & 3;
      int m0 = mt * 64, n0 = nt * 64;
      int bro = (d - 1) * 256;
      f4v acc[2][2] = {};
      for (int kt = 0; kt < 256; kt += 32) {
        __syncthreads();
        {
          int col = tid & 63, kk0 = (tid >> 6) * 8;
#pragma unroll
          for (int j = 0; j < 8; ++j) {
            int k = kt + kk0 + j;
            Bh[col][kk0 + j] = QSh[(bro + k) * 256 + n0 + col];
            Bl[col][kk0 + j] = QSl[(bro + k) * 256 + n0 + col];
          }
        }
        __syncthreads();
#pragma unroll
        for (int aq = 0; aq < 2; ++aq) {
          s8v ah = *reinterpret_cast<const s8v*>(&QSh[(m0 + wr * 32 + aq * 16 + l15) * 256 + kt + q8]);
          s8v al = *reinterpret_cast<const s8v*>(&QSl[(m0 + wr * 32 + aq * 16 + l15) * 256 + kt + q8]);
#pragma unroll
          for (int bq = 0; bq < 2; ++bq) {
            s8v bh = *reinterpret_cast<const s8v*>(&Bh[wc * 32 + bq * 16 + l15][q8]);
            s8v bl = *reinterpret_cast<const s8v*>(&Bl[wc * 32 + bq * 16 + l15][q8]);
            acc[aq][bq] = __builtin_amdgcn_mfma_f32_16x16x32_bf16(ah, bh, acc[aq][bq], 0, 0, 0);
            acc[aq][bq] = __builtin_amdgcn_mfma_f32_16x16x32_bf16(ah, bl, acc[aq][bq], 0, 0, 0);
            acc[aq][bq] = __builtin_amdgcn_mfma_f32_16x16x32_bf16(al, bh, acc[aq][bq], 0, 0, 0);
          }
        }
      }
#pragma unroll
      for (int aq = 0; aq < 2; ++aq)
#pragma unroll
        for (int bq = 0; bq < 2; ++bq)
#pragma unroll
          for (int r = 0; r < 4; ++r) {
            int gm = m0 + wr * 32 + aq * 16 + quad * 4 + r;
            int gn = n0 + wc * 32 + bq * 16 + l15;
            float v = acc[aq][bq][r];
            unsigned short hi = f2bf(v);
            QSh[(d * 256 + gm) * 256 + gn] = hi;
            QSl[(d * 256 + gm) * 256 + gn] = f2bf(v - bf2f(hi));
          }
    }
    if (d < 8) gbar(&ctrs[bc++], 128);
  }
}

// ---------------------------------------------------------------------------
// u_bf16 = bf16(x @ B) : M=16384, K=1024, N=256. grid(128,2)
__global__ __launch_bounds__(256) void k_gemm_u(const float* __restrict__ x,
                                                const unsigned short* __restrict__ Bt,
                                                unsigned short* __restrict__ u){
  __shared__ unsigned short Atile[128][40];
  __shared__ unsigned short Btile[128][40];
  int tid = threadIdx.x;
  int m0 = blockIdx.x * 128, n0 = blockIdx.y * 128;
  int w = tid >> 6, lane = tid & 63;
  int wr = w >> 1, wc = w & 1;
  int l15 = lane & 15, quad = lane >> 4;
  int q8 = quad * 8;
  f4v acc[4][4] = {};
  for (int kt = 0; kt < 1024; kt += 32) {
    __syncthreads();
#pragma unroll
    for (int q = 0; q < 4; ++q) {
      int id = q * 256 + tid;
      int row = id >> 3, c4 = id & 7;
      float4 vv = *reinterpret_cast<const float4*>(&x[(m0 + row) * 1024 + kt + c4 * 4]);
      ushort4 hv;
      hv.x = f2bf(vv.x); hv.y = f2bf(vv.y); hv.z = f2bf(vv.z); hv.w = f2bf(vv.w);
      *reinterpret_cast<ushort4*>(&Atile[row][c4 * 4]) = hv;
    }
#pragma unroll
    for (int q = 0; q < 2; ++q) {
      int id = q * 256 + tid;
      int row = id >> 2, c8 = id & 3;
      uint4 vv = *reinterpret_cast<const uint4*>(&Bt[(n0 + row) * 1024 + kt + c8 * 8]);
      *reinterpret_cast<uint4*>(&Btile[row][c8 * 8]) = vv;
    }
    __syncthreads();
    s8v af[4], bf[4];
#pragma unroll
    for (int aq = 0; aq < 4; ++aq)
      af[aq] = *reinterpret_cast<const s8v*>(&Atile[wr * 64 + aq * 16 + l15][q8]);
#pragma unroll
    for (int bq = 0; bq < 4; ++bq)
      bf[bq] = *reinterpret_cast<const s8v*>(&Btile[wc * 64 + bq * 16 + l15][q8]);
#pragma unroll
    for (int aq = 0; aq < 4; ++aq)
#pragma unroll
      for (int bq = 0; bq < 4; ++bq)
        acc[aq][bq] = __builtin_amdgcn_mfma_f32_16x16x32_bf16(af[aq], bf[bq], acc[aq][bq], 0, 0, 0);
  }
#pragma unroll
  for (int aq = 0; aq < 4; ++aq)
#pragma unroll
    for (int bq = 0; bq < 4; ++bq)
#pragma unroll
      for (int r = 0; r < 4; ++r) {
        int gm = m0 + wr * 64 + aq * 16 + quad * 4 + r;
        int gn = n0 + wc * 64 + bq * 16 + l15;
        u[gm * 256 + gn] = f2bf(acc[aq][bq][r]);
      }
}

// ---------------------------------------------------------------------------
// phase 1: per-(b,subchunk) local scan, L=16, 64 blocks x 16 units.
// writes hs (bf16 local states) and subchunk finals into g0 rows (k+1)*8+b.
// block 0 also copies h0 into g0 rows 0..7.
__global__ __launch_bounds__(256, 1) void k_phase1(const unsigned short* __restrict__ u,
                                                   const unsigned short* __restrict__ Et,
                                                   unsigned short* __restrict__ hs,
                                                   float* __restrict__ g0,
                                                   const float* __restrict__ h0){
  __shared__ unsigned short hbuf[2][16][264];
  int tid = threadIdx.x, w = tid >> 6, lane = tid & 63;
  int l15 = lane & 15, quad = lane >> 4;
  int U0 = blockIdx.x * 16;
  s8v e[4][8];
#pragma unroll
  for (int ct = 0; ct < 4; ++ct) {
    int col = w * 64 + ct * 16 + l15;
#pragma unroll
    for (int kt = 0; kt < 8; ++kt)
      e[ct][kt] = *reinterpret_cast<const s8v*>(&Et[col * 256 + kt * 32 + quad * 8]);
  }
  int rowbase[4];
#pragma unroll
  for (int r = 0; r < 4; ++r) {
    int g = U0 + quad * 4 + r;
    rowbase[r] = ((g >> 7) * 2048 + (g & 127) * 16) * 256;
  }
  for (int i = tid; i < 16 * 264; i += 256) hbuf[0][0][i] = 0;
  if (blockIdx.x == 0)
    for (int i = tid; i < 2048; i += 256) g0[i] = h0[i];
  f4v acc[4] = {};
  float uv[4][4];
#pragma unroll
  for (int r = 0; r < 4; ++r)
#pragma unroll
    for (int ct = 0; ct < 4; ++ct)
      uv[r][ct] = bf2f(u[rowbase[r] + w * 64 + ct * 16 + l15]);
  __syncthreads();
  int cur = 0;
  for (int t = 0; t < 16; ++t) {
    s8v af[8];
#pragma unroll
    for (int kt = 0; kt < 8; ++kt)
      af[kt] = *reinterpret_cast<const s8v*>(&hbuf[cur][l15][kt * 32 + quad * 8]);
    float uvn[4][4];
    if (t < 15)
#pragma unroll
      for (int r = 0; r < 4; ++r)
#pragma unroll
        for (int ct = 0; ct < 4; ++ct)
          uvn[r][ct] = bf2f(u[rowbase[r] + (t + 1) * 256 + w * 64 + ct * 16 + l15]);
#pragma unroll
    for (int kt = 0; kt < 8; ++kt)
#pragma unroll
      for (int ct = 0; ct < 4; ++ct)
        acc[ct] = __builtin_amdgcn_mfma_f32_16x16x32_bf16(af[kt], e[ct][kt], acc[ct], 0, 0, 0);
    int nxt = cur ^ 1;
#pragma unroll
    for (int ct = 0; ct < 4; ++ct)
#pragma unroll
      for (int r = 0; r < 4; ++r) {
        acc[ct][r] += uv[r][ct];
        hbuf[nxt][quad * 4 + r][w * 64 + ct * 16 + l15] = f2bf(acc[ct][r]);
      }
    __syncthreads();
    int ul = w * 4 + quad, seg = l15;
    uint4 d0 = *reinterpret_cast<const uint4*>(&hbuf[nxt][ul][seg * 16]);
    uint4 d1 = *reinterpret_cast<const uint4*>(&hbuf[nxt][ul][seg * 16 + 8]);
    int g = U0 + ul;
    int hrow = ((g >> 7) * 2048 + (g & 127) * 16 + t) * 256;
    *reinterpret_cast<uint4*>(&hs[hrow + seg * 16]) = d0;
    *reinterpret_cast<uint4*>(&hs[hrow + seg * 16 + 8]) = d1;
    if (t < 15)
#pragma unroll
      for (int r = 0; r < 4; ++r)
#pragma unroll
        for (int ct = 0; ct < 4; ++ct)
          uv[r][ct] = uvn[r][ct];
    cur = nxt;
  }
#pragma unroll
  for (int ct = 0; ct < 4; ++ct)
#pragma unroll
    for (int r = 0; r < 4; ++r) {
      int g = U0 + quad * 4 + r;
      int k = g & 127, b = g >> 7;
      if (k < 127)
        g0[((k + 1) * 8 + b) * 256 + w * 64 + ct * 16 + l15] = acc[ct][r];
    }
}

// ---------------------------------------------------------------------------
// scan mega-kernel (80 blocks): 7 Kogge-Stone rounds over 1024 carry rows
// (row = k*8+b). Round rd: gOut = gIn + shift_{8<<rd}(gIn) @ A16^{2^rd}.
// Blocks 64..79 concurrently square the power for the next round.
__global__ __launch_bounds__(256, 1) void k_scan7(float* __restrict__ g0, float* __restrict__ g1,
    const unsigned short* __restrict__ QSh, const unsigned short* __restrict__ QSl,
    unsigned short* __restrict__ Sh0, unsigned short* __restrict__ Sl0,
    unsigned short* __restrict__ Sh1, unsigned short* __restrict__ Sl1,
    unsigned* __restrict__ ctrs){
  __shared__ unsigned short Bh[64][40], Bl[64][40];
  int tid = threadIdx.x, lane = tid & 63, w = tid >> 6;
  int wr = w >> 1, wc = w & 1, l15 = lane & 15, quad = lane >> 4, q8 = quad * 8;
  int bid = blockIdx.x;
  const unsigned short* cSh = QSh + 15 * 65536;   // A16^T = QS[15]
  const unsigned short* cSl = QSl + 15 * 65536;
  float* gi = g0;
  float* go = g1;
#pragma unroll 1
  for (int rd = 0; rd < 7; ++rd) {
    int rs = 8 << rd;
    if (bid < 64) {
      int mt = bid >> 2, nt = bid & 3;
      int m0 = mt * 64, n0 = nt * 64;
      f4v acc[2][2];
#pragma unroll
      for (int aq = 0; aq < 2; ++aq)
#pragma unroll
        for (int bq = 0; bq < 2; ++bq)
#pragma unroll
          for (int r = 0; r < 4; ++r)
            acc[aq][bq][r] = gi[(m0 + wr * 32 + aq * 16 + quad * 4 + r) * 256 +
                                n0 + wc * 32 + bq * 16 + l15];
      for (int kt = 0; kt < 256; kt += 32) {
        s8v ah[2], al[2];
#pragma unroll
        for (int aq = 0; aq < 2; ++aq) {
          int ar = m0 + wr * 32 + aq * 16 + l15 - rs;
          if (ar >= 0) split8(&gi[ar * 256 + kt + q8], ah[aq], al[aq]);
          else { zero8(ah[aq]); zero8(al[aq]); }
        }
#pragma unroll
        for (int bq = 0; bq < 2; ++bq) {
          int bc = n0 + wc * 32 + bq * 16 + l15;
          s8v bh = *reinterpret_cast<const s8v*>(&cSh[bc * 256 + kt + q8]);
          s8v bl = *reinterpret_cast<const s8v*>(&cSl[bc * 256 + kt + q8]);
#pragma unroll
          for (int aq = 0; aq < 2; ++aq) {
            acc[aq][bq] = __builtin_amdgcn_mfma_f32_16x16x32_bf16(ah[aq], bh, acc[aq][bq], 0, 0, 0);
            acc[aq][bq] = __builtin_amdgcn_mfma_f32_16x16x32_bf16(ah[aq], bl, acc[aq][bq], 0, 0, 0);
            acc[aq][bq] = __builtin_amdgcn_mfma_f32_16x16x32_bf16(al[aq], bh, acc[aq][bq], 0, 0, 0);
          }
        }
      }
#pragma unroll
      for (int aq = 0; aq < 2; ++aq)
#pragma unroll
        for (int bq = 0; bq < 2; ++bq)
#pragma unroll
          for (int r = 0; r < 4; ++r)
            go[(m0 + wr * 32 + aq * 16 + quad * 4 + r) * 256 +
               n0 + wc * 32 + bq * 16 + l15] = acc[aq][bq][r];
    } else if (rd < 6) {
      // square the power: S' = S @ S
      unsigned short* dh = (rd & 1) ? Sh1 : Sh0;
      unsigned short* dl = (rd & 1) ? Sl1 : Sl0;
      int t = bid - 64;
      int m0 = (t >> 2) * 64, n0 = (t & 3) * 64;
      f4v acc[2][2] = {};
      for (int kt = 0; kt < 256; kt += 32) {
        __syncthreads();
        {
          int col = tid & 63, kk0 = (tid >> 6) * 8;
#pragma unroll
          for (int j = 0; j < 8; ++j) {
            int k = kt + kk0 + j;
            Bh[col][kk0 + j] = cSh[k * 256 + n0 + col];
            Bl[col][kk0 + j] = cSl[k * 256 + n0 + col];
          }
        }
        __syncthreads();
#pragma unroll
        for (int aq = 0; aq < 2; ++aq) {
          s8v ah = *reinterpret_cast<const s8v*>(&cSh[(m0 + wr * 32 + aq * 16 + l15) * 256 + kt + q8]);
          s8v al = *reinterpret_cast<const s8v*>(&cSl[(m0 + wr * 32 + aq * 16 + l15) * 256 + kt + q8]);
#pragma unroll
          for (int bq = 0; bq < 2; ++bq) {
            s8v bh = *reinterpret_cast<const s8v*>(&Bh[wc * 32 + bq * 16 + l15][q8]);
            s8v bl = *reinterpret_cast<const s8v*>(&Bl[wc * 32 + bq * 16 + l15][q8]);
            acc[aq][bq] = __builtin_amdgcn_mfma_f32_16x16x32_bf16(ah, bh, acc[aq][bq], 0, 0, 0);
            acc[aq][bq] = __builtin_amdgcn_mfma_f32_16x16x32_bf16(ah, bl, acc[aq][bq], 0, 0, 0);
            acc[aq][bq] = __builtin_amdgcn_mfma_f32_16x16x32_bf16(al, bh, acc[aq][bq], 0, 0, 0);
          }
        }
      }
#pragma unroll
      for (int aq = 0; aq < 2; ++aq)
#pragma unroll
        for (int bq = 0; bq < 2; ++bq)
#pragma unroll
          for (int r = 0; r < 4; ++r) {
            int gm = m0 + wr * 32 + aq * 16 + quad * 4 + r;
            int gn = n0 + wc * 32 + bq * 16 + l15;
            float v = acc[aq][bq][r];
            unsigned short hi = f2bf(v);
            dh[gm * 256 + gn] = hi;
            dl[gm * 256 + gn] = f2bf(v - bf2f(hi));
          }
    }
    if (rd < 6) {
      gbar(&ctrs[8 + rd], 80);
      cSh = (rd & 1) ? Sh1 : Sh0;
      cSl = (rd & 1) ? Sl1 : Sl0;
      float* tg = gi; gi = go; go = tg;
    }
  }
}

// ---------------------------------------------------------------------------
// carry expansion GEMM: hs[(b*2048 + k*16 + t)*256 + n] += carry[k*8+b] @ A_d^{t+1}
// = carry(1024x256) @ PW(256x4096) with PW[col=(t,n)][m] = QS[t] rows (direct).
__global__ __launch_bounds__(256) void k_carryexp(const float* __restrict__ g,
    const unsigned short* __restrict__ QSh, const unsigned short* __restrict__ QSl,
    unsigned short* __restrict__ hs){
  int tid = threadIdx.x, lane = tid & 63, w = tid >> 6;
  int wr = w >> 1, wc = w & 1, l15 = lane & 15, quad = lane >> 4, q8 = quad * 8;
  for (int t = blockIdx.x; t < 1024; t += 256) {
    int mt = t >> 6, nt = t & 63;
    int m0 = mt * 64, n0 = nt * 64;
    f4v acc[2][2] = {};
    for (int kt = 0; kt < 256; kt += 32) {
      s8v ah[2], al[2];
#pragma unroll
      for (int aq = 0; aq < 2; ++aq)
        split8(&g[(m0 + wr * 32 + aq * 16 + l15) * 256 + kt + q8], ah[aq], al[aq]);
#pragma unroll
      for (int bq = 0; bq < 2; ++bq) {
        int bc = n0 + wc * 32 + bq * 16 + l15;
        s8v bh = *reinterpret_cast<const s8v*>(&QSh[bc * 256 + kt + q8]);
        s8v bl = *reinterpret_cast<const s8v*>(&QSl[bc * 256 + kt + q8]);
#pragma unroll
        for (int aq = 0; aq < 2; ++aq) {
          acc[aq][bq] = __builtin_amdgcn_mfma_f32_16x16x32_bf16(ah[aq], bh, acc[aq][bq], 0, 0, 0);
          acc[aq][bq] = __builtin_amdgcn_mfma_f32_16x16x32_bf16(ah[aq], bl, acc[aq][bq], 0, 0, 0);
          acc[aq][bq] = __builtin_amdgcn_mfma_f32_16x16x32_bf16(al[aq], bh, acc[aq][bq], 0, 0, 0);
        }
      }
    }
#pragma unroll
    for (int aq = 0; aq < 2; ++aq)
#pragma unroll
      for (int bq = 0; bq < 2; ++bq)
#pragma unroll
        for (int r = 0; r < 4; ++r) {
          int gm = m0 + wr * 32 + aq * 16 + quad * 4 + r;   // = k*8+b
          int gn = n0 + wc * 32 + bq * 16 + l15;            // = t0*256+n
          int k = gm >> 3, b = gm & 7, t0 = gn >> 8, nn = gn & 255;
          int idx = (b * 2048 + k * 16 + t0) * 256 + nn;
          hs[idx] = f2bf(bf2f(hs[idx]) + acc[aq][bq][r]);
        }
  }
}

// ---------------------------------------------------------------------------
// y = hs @ C + x*D : M=16384, K=256, N=1024. grid(128,8)
__global__ __launch_bounds__(256) void k_gemm_y(const unsigned short* __restrict__ hs,
                                                const unsigned short* __restrict__ Ct,
                                                const float* __restrict__ x,
                                                const float* __restrict__ D,
                                                float* __restrict__ y){
  __shared__ unsigned short Atile[128][40];
  __shared__ unsigned short Btile[128][40];
  int tid = threadIdx.x;
  int m0 = blockIdx.x * 128, n0 = blockIdx.y * 128;
  int w = tid >> 6, lane = tid & 63;
  int wr = w >> 1, wc = w & 1;
  int l15 = lane & 15, quad = lane >> 4;
  int q8 = quad * 8;
  f4v acc[4][4] = {};
  for (int kt = 0; kt < 256; kt += 32) {
    __syncthreads();
#pragma unroll
    for (int q = 0; q < 2; ++q) {
      int id = q * 256 + tid;
      int row = id >> 2, c8 = id & 3;
      uint4 av = *reinterpret_cast<const uint4*>(&hs[(m0 + row) * 256 + kt + c8 * 8]);
      *reinterpret_cast<uint4*>(&Atile[row][c8 * 8]) = av;
      uint4 bv = *reinterpret_cast<const uint4*>(&Ct[(n0 + row) * 256 + kt + c8 * 8]);
      *reinterpret_cast<uint4*>(&Btile[row][c8 * 8]) = bv;
    }
    __syncthreads();
    s8v af[4], bf[4];
#pragma unroll
    for (int aq = 0; aq < 4; ++aq)
      af[aq] = *reinterpret_cast<const s8v*>(&Atile[wr * 64 + aq * 16 + l15][q8]);
#pragma unroll
    for (int bq = 0; bq < 4; ++bq)
      bf[bq] = *reinterpret_cast<const s8v*>(&Btile[wc * 64 + bq * 16 + l15][q8]);
#pragma unroll
    for (int aq = 0; aq < 4; ++aq)
#pragma unroll
      for (int bq = 0; bq < 4; ++bq)
        acc[aq][bq] = __builtin_amdgcn_mfma_f32_16x16x32_bf16(af[aq], bf[bq], acc[aq][bq], 0, 0, 0);
  }
#pragma unroll
  for (int bq = 0; bq < 4; ++bq) {
    int gn = n0 + wc * 64 + bq * 16 + l15;
    float dv = D[gn];
#pragma unroll
    for (int aq = 0; aq < 4; ++aq)
#pragma unroll
      for (int r = 0; r < 4; ++r) {
        int gm = m0 + wr * 64 + aq * 16 + quad * 4 + r;
        y[gm * 1024 + gn] = acc[aq][bq][r] + x[gm * 1024 + gn] * dv;
      }
  }
}

// ---------------------------------------------------------------------------
extern "C" void kernel_launch(void* const* d_in, const int* in_sizes, int n_in,
                              void* d_out, int out_size, void* d_ws, size_t ws_size,
                              hipStream_t stream) {
  (void)in_sizes; (void)n_in; (void)out_size; (void)ws_size;
  const float* x  = (const float*)d_in[0];
  const float* A  = (const float*)d_in[1];
  const float* B  = (const float*)d_in[2];
  const float* C  = (const float*)d_in[3];
  const float* D  = (const float*)d_in[4];
  const float* h0 = (const float*)d_in[5];
  float* y = (float*)d_out;

  char* ws = (char*)d_ws;
  size_t off = 0;
  auto alloc = [&](size_t bytes) { void* p = ws + off; off += (bytes + 255) & ~(size_t)255; return p; };
  float* Mt  = (float*)alloc(262144);
  float* Tp0 = (float*)alloc(262144);
  float* Tp1 = (float*)alloc(262144);
  unsigned short* QSh = (unsigned short*)alloc(2097152);  // 16 x 256x256 hi
  unsigned short* QSl = (unsigned short*)alloc(2097152);  // 16 x 256x256 lo
  unsigned short* Et  = (unsigned short*)alloc(131072);
  unsigned short* Sh0 = (unsigned short*)alloc(131072);
  unsigned short* Sl0 = (unsigned short*)alloc(131072);
  unsigned short* Sh1 = (unsigned short*)alloc(131072);
  unsigned short* Sl1 = (unsigned short*)alloc(131072);
  float* g0 = (float*)alloc(1048576);
  float* g1 = (float*)alloc(1048576);
  unsigned short* Bt = (unsigned short*)alloc(524288);
  unsigned short* Ct = (unsigned short*)alloc(524288);
  unsigned short* u  = (unsigned short*)alloc(8388608);
  unsigned short* hs = (unsigned short*)alloc(8388608);
  unsigned* ctrs = (unsigned*)alloc(256);

  hipMemsetAsync(ctrs, 0, 256, stream);
  k_prep<<<2304, 256, 0, stream>>>(A, B, C, Mt, Tp0, Bt, Ct);
  k_chain<<<128, 256, 0, stream>>>(Mt, Tp0, Tp1, QSh, QSl, Et, ctrs);
  k_gemm_u<<<dim3(128, 2), 256, 0, stream>>>(x, Bt, u);
  k_phase1<<<64, 256, 0, stream>>>(u, Et, hs, g0, h0);
  k_scan7<<<80, 256, 0, stream>>>(g0, g1, QSh, QSl, Sh0, Sl0, Sh1, Sl1, ctrs);
  k_carryexp<<<256, 256, 0, stream>>>(g1, QSh, QSl, hs);
  k_gemm_y<<<dim3(128, 8), 256, 0, stream>>>(hs, Ct, x, D, y);
}